// Round 8
// baseline (1559.553 us; speedup 1.0000x reference)
//
#include <hip/hip_runtime.h>
#include <hip/hip_bf16.h>

#define DH 256
#define DE 32
#define NLAYERS 5
#define NEG_SLOPE 0.2f
#define EPSV 1e-16f
#define SEG 512

typedef __attribute__((ext_vector_type(8))) short bf16x8;
typedef __attribute__((ext_vector_type(4))) float f32x4;

__device__ inline float bf2f(unsigned short u) {
    unsigned x = ((unsigned)u) << 16;
    union { unsigned u; float f; } c; c.u = x; return c.f;
}
__device__ inline unsigned short f2bf(float f) {
    union { float f; unsigned u; } c; c.f = f;
    unsigned b = c.u;
    unsigned r = (b + 0x7FFF + ((b >> 16) & 1)) >> 16;
    return (unsigned short)r;
}

// ---------------------------------------------------------------- CSR build
__global__ void k_count(const int* __restrict__ dst, int* __restrict__ cnt, int E) {
    int e = blockIdx.x * 256 + threadIdx.x;
    if (e < E) atomicAdd(&cnt[dst[e]], 1);
}

__global__ void k_part(const int* __restrict__ cnt, int* __restrict__ part, int n) {
    int b = blockIdx.x, t = threadIdx.x;  // 512 threads
    int i = b * SEG + t;
    int v = (i < n) ? cnt[i] : 0;
    for (int d = 32; d; d >>= 1) v += __shfl_down(v, d);
    __shared__ int ws[8];
    int lane = t & 63, w = t >> 6;
    if (lane == 0) ws[w] = v;
    __syncthreads();
    if (t == 0) {
        int s = 0;
        #pragma unroll
        for (int k = 0; k < 8; ++k) s += ws[k];
        part[b] = s;
    }
}

__global__ void k_scanp(const int* __restrict__ part, int* __restrict__ base,
                        int* __restrict__ off, int nblk, int n, int total) {
    int t = threadIdx.x;
    int lane = t & 63, w = t >> 6;
    __shared__ int wsum[2];
    int v = (t < nblk) ? part[t] : 0;
    int incl = v;
    for (int d = 1; d < 64; d <<= 1) {
        int u = __shfl_up(incl, d);
        if (lane >= d) incl += u;
    }
    if (lane == 63) wsum[w] = incl;
    __syncthreads();
    int add = (w == 1) ? wsum[0] : 0;
    if (t < nblk) base[t] = incl - v + add;
    if (t == 0) off[n] = total;
}

__global__ void k_emit(const int* __restrict__ cnt, const int* __restrict__ base,
                       int* __restrict__ off, float* __restrict__ invd, int n) {
    int b = blockIdx.x, t = threadIdx.x;  // 512 threads
    int i = b * SEG + t;
    int c = (i < n) ? cnt[i] : 0;
    int lane = t & 63, w = t >> 6;
    int incl = c;
    for (int d = 1; d < 64; d <<= 1) {
        int u = __shfl_up(incl, d);
        if (lane >= d) incl += u;
    }
    __shared__ int ws[8];
    if (lane == 63) ws[w] = incl;
    __syncthreads();
    int add = 0;
    for (int k = 0; k < w; ++k) add += ws[k];
    if (i < n) {
        off[i] = base[b] + add + incl - c;
        invd[i] = 1.0f / (float)max(c, 1);
    }
}

__global__ void k_fill(const int* __restrict__ src, const int* __restrict__ dst,
                       const int* __restrict__ off, int* __restrict__ cur,
                       int* __restrict__ csrc, int* __restrict__ ceid, int E) {
    int e = blockIdx.x * 256 + threadIdx.x;
    if (e >= E) return;
    int d = dst[e];
    int p = off[d] + atomicAdd(&cur[d], 1);
    csrc[p] = src[e];
    ceid[p] = e;
}

// ---------------------------------------------------------------- edge precompute
__global__ void k_we_ae(const float* __restrict__ We, const float* __restrict__ a_e,
                        float* __restrict__ out) {
    int t = threadIdx.x;
    if (t >= NLAYERS * DE) return;
    int l = t >> 5, d = t & 31;
    const float* w = We + ((size_t)l * DE + d) * DH;
    const float* ae = a_e + (size_t)l * DH;
    float s = 0.f;
    for (int j = 0; j < DH; ++j) s += w[j] * ae[j];
    out[t] = s;
}

// gather-direction: p-indexed, random full-row read of ea, coalesced writes
__global__ void k_elogit(const float* __restrict__ ea, const float* __restrict__ we_ae,
                         const int* __restrict__ ceid, float* __restrict__ elogp, int E) {
    __shared__ float w[NLAYERS * DE];
    if (threadIdx.x < NLAYERS * DE) w[threadIdx.x] = we_ae[threadIdx.x];
    __syncthreads();
    int p = blockIdx.x * 256 + threadIdx.x;
    if (p >= E) return;
    int e = ceid[p];
    const float4* q = (const float4*)(ea + (size_t)e * DE);
    float r[NLAYERS] = {0, 0, 0, 0, 0};
    #pragma unroll
    for (int i = 0; i < DE / 4; ++i) {
        float4 x = q[i];
        #pragma unroll
        for (int l = 0; l < NLAYERS; ++l) {
            r[l] += x.x * w[l * DE + i * 4 + 0] + x.y * w[l * DE + i * 4 + 1] +
                    x.z * w[l * DE + i * 4 + 2] + x.w * w[l * DE + i * 4 + 3];
        }
    }
    #pragma unroll
    for (int l = 0; l < NLAYERS; ++l) elogp[(size_t)l * E + p] = r[l];
}

// ---------------------------------------------------------------- weight transpose fp32 -> bf16
__global__ void k_wt(const float* __restrict__ Wg, const float* __restrict__ Ws,
                     const float* __restrict__ Wn, unsigned short* __restrict__ Wt) {
    __shared__ float tile[32][33];
    int z = blockIdx.z;
    const float* W = z < 5 ? Wg + (size_t)z * DH * DH
                   : (z < 10 ? Ws + (size_t)(z - 5) * DH * DH
                             : Wn + (size_t)(z - 10) * DH * DH);
    unsigned short* out = Wt + (size_t)z * DH * DH;
    int c0 = blockIdx.x * 32, r0 = blockIdx.y * 32;
    int tx = threadIdx.x, ty = threadIdx.y;
    for (int j = ty; j < 32; j += 8) tile[j][tx] = W[(size_t)(r0 + j) * DH + c0 + tx];
    __syncthreads();
    for (int j = ty; j < 32; j += 8)
        out[(size_t)(c0 + j) * DH + r0 + tx] = f2bf(tile[tx][j]);
}

// ---------------------------------------------------------------- lin0 (bf16 out)
__global__ void k_lin0(const float* __restrict__ x, const float* __restrict__ W0,
                       const float* __restrict__ b0, unsigned short* __restrict__ hb, int n) {
    int node = blockIdx.x;
    int c = threadIdx.x;
    if (node >= n) return;
    float x0 = x[(size_t)node * 3 + 0];
    float x1 = x[(size_t)node * 3 + 1];
    float x2 = x[(size_t)node * 3 + 2];
    float v = b0[c] + x0 * W0[c] + x1 * W0[DH + c] + x2 * W0[2 * DH + c];
    hb[(size_t)node * DH + c] = f2bf(v);
}

// ---------------------------------------------------------------- fused logit+softmax+aggregate
// Wave per node; edge exp-logits in 4 lane-owned regs (deg<=256); 8 rows in flight.
__global__ void k_attn(const int* __restrict__ off, const int* __restrict__ csrc,
                       const float* __restrict__ ssrc, const float* __restrict__ sdst,
                       const float* __restrict__ elogp, const unsigned short* __restrict__ hg,
                       const float* __restrict__ bias, unsigned short* __restrict__ h1, int n) {
    int wave = threadIdx.x >> 6, lane = threadIdx.x & 63;
    int node = blockIdx.x * 4 + wave;
    if (node >= n) return;
    int p0 = off[node], p1 = off[node + 1];
    int deg = p1 - p0;
    float sd = sdst[node];
    int c = lane * 4;
    float a0 = 0.f, a1 = 0.f, a2 = 0.f, a3 = 0.f;

    if (deg <= 256) {
        float ex0 = 0.f, ex1 = 0.f, ex2 = 0.f, ex3 = 0.f;
        int cs0 = 0, cs1 = 0, cs2 = 0, cs3 = 0;
        float m = -3.4e38f;
        {
            int p = p0 + lane;
            if (p < p1) { cs0 = csrc[p]; float r = ssrc[cs0] + sd + elogp[p];
                          r = r > 0.f ? r : NEG_SLOPE * r; ex0 = r; m = fmaxf(m, r); }
            p += 64;
            if (p < p1) { cs1 = csrc[p]; float r = ssrc[cs1] + sd + elogp[p];
                          r = r > 0.f ? r : NEG_SLOPE * r; ex1 = r; m = fmaxf(m, r); }
            p += 64;
            if (p < p1) { cs2 = csrc[p]; float r = ssrc[cs2] + sd + elogp[p];
                          r = r > 0.f ? r : NEG_SLOPE * r; ex2 = r; m = fmaxf(m, r); }
            p += 64;
            if (p < p1) { cs3 = csrc[p]; float r = ssrc[cs3] + sd + elogp[p];
                          r = r > 0.f ? r : NEG_SLOPE * r; ex3 = r; m = fmaxf(m, r); }
        }
        for (int d = 32; d; d >>= 1) m = fmaxf(m, __shfl_xor(m, d));
        float den = 0.f;
        {
            int p = p0 + lane;
            if (p < p1) { ex0 = expf(ex0 - m); den += ex0; }
            p += 64;
            if (p < p1) { ex1 = expf(ex1 - m); den += ex1; }
            p += 64;
            if (p < p1) { ex2 = expf(ex2 - m); den += ex2; }
            p += 64;
            if (p < p1) { ex3 = expf(ex3 - m); den += ex3; }
        }
        for (int d = 32; d; d >>= 1) den += __shfl_xor(den, d);
        float inv = 1.0f / (den + EPSV);

        #define EDGEA(u, WV, SV) { int q = p + (u) - p0; int jj = q >> 6; int sl = q & 63; \
            float ev = ex0; if (jj == 1) ev = ex1; else if (jj == 2) ev = ex2; else if (jj == 3) ev = ex3; \
            int cv = cs0; if (jj == 1) cv = cs1; else if (jj == 2) cv = cs2; else if (jj == 3) cv = cs3; \
            WV = __shfl(ev, sl) * inv; SV = __shfl(cv, sl); }

        int p = p0;
        for (; p + 8 <= p1; p += 8) {
            float w0, w1, w2, w3, w4, w5, w6, w7;
            int s0, s1, s2, s3, s4, s5, s6, s7;
            EDGEA(0, w0, s0) EDGEA(1, w1, s1) EDGEA(2, w2, s2) EDGEA(3, w3, s3)
            EDGEA(4, w4, s4) EDGEA(5, w5, s5) EDGEA(6, w6, s6) EDGEA(7, w7, s7)
            ushort4 v0 = *(const ushort4*)(hg + (size_t)s0 * DH + c);
            ushort4 v1 = *(const ushort4*)(hg + (size_t)s1 * DH + c);
            ushort4 v2 = *(const ushort4*)(hg + (size_t)s2 * DH + c);
            ushort4 v3 = *(const ushort4*)(hg + (size_t)s3 * DH + c);
            ushort4 v4 = *(const ushort4*)(hg + (size_t)s4 * DH + c);
            ushort4 v5 = *(const ushort4*)(hg + (size_t)s5 * DH + c);
            ushort4 v6 = *(const ushort4*)(hg + (size_t)s6 * DH + c);
            ushort4 v7 = *(const ushort4*)(hg + (size_t)s7 * DH + c);
            a0 += w0 * bf2f(v0.x) + w1 * bf2f(v1.x) + w2 * bf2f(v2.x) + w3 * bf2f(v3.x)
                + w4 * bf2f(v4.x) + w5 * bf2f(v5.x) + w6 * bf2f(v6.x) + w7 * bf2f(v7.x);
            a1 += w0 * bf2f(v0.y) + w1 * bf2f(v1.y) + w2 * bf2f(v2.y) + w3 * bf2f(v3.y)
                + w4 * bf2f(v4.y) + w5 * bf2f(v5.y) + w6 * bf2f(v6.y) + w7 * bf2f(v7.y);
            a2 += w0 * bf2f(v0.z) + w1 * bf2f(v1.z) + w2 * bf2f(v2.z) + w3 * bf2f(v3.z)
                + w4 * bf2f(v4.z) + w5 * bf2f(v5.z) + w6 * bf2f(v6.z) + w7 * bf2f(v7.z);
            a3 += w0 * bf2f(v0.w) + w1 * bf2f(v1.w) + w2 * bf2f(v2.w) + w3 * bf2f(v3.w)
                + w4 * bf2f(v4.w) + w5 * bf2f(v5.w) + w6 * bf2f(v6.w) + w7 * bf2f(v7.w);
        }
        for (; p < p1; ++p) {
            float w0; int s0;
            EDGEA(0, w0, s0)
            ushort4 v0 = *(const ushort4*)(hg + (size_t)s0 * DH + c);
            a0 += w0 * bf2f(v0.x); a1 += w0 * bf2f(v0.y);
            a2 += w0 * bf2f(v0.z); a3 += w0 * bf2f(v0.w);
        }
        #undef EDGEA
    } else {
        // correctness fallback for deg > 256
        float m = -3.4e38f;
        for (int p = p0 + lane; p < p1; p += 64) {
            float r = ssrc[csrc[p]] + sd + elogp[p];
            r = r > 0.f ? r : NEG_SLOPE * r;
            m = fmaxf(m, r);
        }
        for (int d = 32; d; d >>= 1) m = fmaxf(m, __shfl_xor(m, d));
        float den = 0.f;
        for (int p = p0 + lane; p < p1; p += 64) {
            float r = ssrc[csrc[p]] + sd + elogp[p];
            r = r > 0.f ? r : NEG_SLOPE * r;
            den += expf(r - m);
        }
        for (int d = 32; d; d >>= 1) den += __shfl_xor(den, d);
        float inv = 1.0f / (den + EPSV);
        for (int p = p0; p < p1; ++p) {
            int sn = csrc[p];
            float r = ssrc[sn] + sd + elogp[p];
            r = r > 0.f ? r : NEG_SLOPE * r;
            float a = expf(r - m) * inv;
            ushort4 v = *(const ushort4*)(hg + (size_t)sn * DH + c);
            a0 += a * bf2f(v.x); a1 += a * bf2f(v.y);
            a2 += a * bf2f(v.z); a3 += a * bf2f(v.w);
        }
    }

    float4 bb = *(const float4*)(bias + c);
    ushort4 o;
    o.x = f2bf(fmaxf(a0 + bb.x, 0.f));
    o.y = f2bf(fmaxf(a1 + bb.y, 0.f));
    o.z = f2bf(fmaxf(a2 + bb.z, 0.f));
    o.w = f2bf(fmaxf(a3 + bb.w, 0.f));
    *(ushort4*)(h1 + (size_t)node * DH + c) = o;
}

// ---------------------------------------------------------------- mean aggregate (x8 unroll)
__global__ void k_mean(const int* __restrict__ off, const int* __restrict__ csrc,
                       const unsigned short* __restrict__ h1, const float* __restrict__ inv_deg,
                       unsigned short* __restrict__ mean, int n) {
    int wave = threadIdx.x >> 6, lane = threadIdx.x & 63;
    int node = blockIdx.x * 4 + wave;
    if (node >= n) return;
    int p0 = off[node], p1 = off[node + 1];
    int c = lane * 4;
    float a0 = 0.f, a1 = 0.f, a2 = 0.f, a3 = 0.f;
    int p = p0;
    for (; p + 8 <= p1; p += 8) {
        int s0 = csrc[p],     s1 = csrc[p + 1], s2 = csrc[p + 2], s3 = csrc[p + 3];
        int s4 = csrc[p + 4], s5 = csrc[p + 5], s6 = csrc[p + 6], s7 = csrc[p + 7];
        ushort4 v0 = *(const ushort4*)(h1 + (size_t)s0 * DH + c);
        ushort4 v1 = *(const ushort4*)(h1 + (size_t)s1 * DH + c);
        ushort4 v2 = *(const ushort4*)(h1 + (size_t)s2 * DH + c);
        ushort4 v3 = *(const ushort4*)(h1 + (size_t)s3 * DH + c);
        ushort4 v4 = *(const ushort4*)(h1 + (size_t)s4 * DH + c);
        ushort4 v5 = *(const ushort4*)(h1 + (size_t)s5 * DH + c);
        ushort4 v6 = *(const ushort4*)(h1 + (size_t)s6 * DH + c);
        ushort4 v7 = *(const ushort4*)(h1 + (size_t)s7 * DH + c);
        a0 += bf2f(v0.x) + bf2f(v1.x) + bf2f(v2.x) + bf2f(v3.x)
            + bf2f(v4.x) + bf2f(v5.x) + bf2f(v6.x) + bf2f(v7.x);
        a1 += bf2f(v0.y) + bf2f(v1.y) + bf2f(v2.y) + bf2f(v3.y)
            + bf2f(v4.y) + bf2f(v5.y) + bf2f(v6.y) + bf2f(v7.y);
        a2 += bf2f(v0.z) + bf2f(v1.z) + bf2f(v2.z) + bf2f(v3.z)
            + bf2f(v4.z) + bf2f(v5.z) + bf2f(v6.z) + bf2f(v7.z);
        a3 += bf2f(v0.w) + bf2f(v1.w) + bf2f(v2.w) + bf2f(v3.w)
            + bf2f(v4.w) + bf2f(v5.w) + bf2f(v6.w) + bf2f(v7.w);
    }
    for (; p < p1; ++p) {
        ushort4 v = *(const ushort4*)(h1 + (size_t)csrc[p] * DH + c);
        a0 += bf2f(v.x); a1 += bf2f(v.y); a2 += bf2f(v.z); a3 += bf2f(v.w);
    }
    float inv = inv_deg[node];
    ushort4 o;
    o.x = f2bf(a0 * inv); o.y = f2bf(a1 * inv);
    o.z = f2bf(a2 * inv); o.w = f2bf(a3 * inv);
    *(ushort4*)(mean + (size_t)node * DH + c) = o;
}

// ---------------------------------------------------------------- final projection (bf16 H)
__global__ void k_out(const unsigned short* __restrict__ h, const float* __restrict__ W1,
                      const float* __restrict__ b1, float* __restrict__ out, int n) {
    int wave = threadIdx.x >> 6, lane = threadIdx.x & 63;
    int row = blockIdx.x * 4 + wave;
    if (row >= n) return;
    ushort4 v = *(const ushort4*)(h + (size_t)row * DH + lane * 4);
    float4 w1 = *(const float4*)(W1 + lane * 4);
    float s = bf2f(v.x) * w1.x + bf2f(v.y) * w1.y + bf2f(v.z) * w1.z + bf2f(v.w) * w1.w;
    for (int d = 32; d; d >>= 1) s += __shfl_down(s, d);
    if (lane == 0) out[row] = s + b1[0];
}

// ---------------------------------------------------------------- MFMA GEMM
// DOTS: fuse ssrc/sdst row-dots (vs asrc/adst) into epilogue via 16-lane
// butterfly + one atomicAdd per row-group (ssrc/sdst pre-zeroed).
template <int TWO, int EPI, int DOTS>
__global__ __launch_bounds__(256) void k_gemm_mfma(
    const unsigned short* __restrict__ A, const unsigned short* __restrict__ Bt,
    const unsigned short* __restrict__ A2, const unsigned short* __restrict__ B2t,
    const float* __restrict__ bias, const unsigned short* __restrict__ resid,
    unsigned short* __restrict__ Cb, int M,
    const float* __restrict__ asrc, const float* __restrict__ adst,
    float* __restrict__ ssrc, float* __restrict__ sdst) {
    const int t = threadIdx.x;
    const int wid = t >> 6, lane = t & 63;
    const int wr = wid >> 1, wc = wid & 1;
    const int bm = blockIdx.x * 128 + wr * 64;
    const int bn = blockIdx.y * 128 + wc * 64;
    const int lrow = lane & 15;
    const int kgrp = (lane >> 4) * 8;

    f32x4 acc[4][4] = {};

    #pragma unroll
    for (int pass = 0; pass <= TWO; ++pass) {
        const unsigned short* Ap = pass ? A2 : A;
        const unsigned short* Bp = pass ? B2t : Bt;
        #pragma unroll 2
        for (int k0 = 0; k0 < DH; k0 += 32) {
            bf16x8 a[4], b[4];
            #pragma unroll
            for (int m = 0; m < 4; ++m)
                a[m] = *(const bf16x8*)(Ap + (size_t)(bm + m * 16 + lrow) * DH + k0 + kgrp);
            #pragma unroll
            for (int n = 0; n < 4; ++n)
                b[n] = *(const bf16x8*)(Bp + (size_t)(bn + n * 16 + lrow) * DH + k0 + kgrp);
            #pragma unroll
            for (int m = 0; m < 4; ++m)
                #pragma unroll
                for (int n = 0; n < 4; ++n)
                    acc[m][n] = __builtin_amdgcn_mfma_f32_16x16x32_bf16(a[m], b[n], acc[m][n], 0, 0, 0);
        }
    }

    float wa[4], wb[4];
    if (DOTS) {
        #pragma unroll
        for (int n = 0; n < 4; ++n) {
            wa[n] = asrc[bn + n * 16 + lrow];
            wb[n] = adst[bn + n * 16 + lrow];
        }
    }

    const int crow0 = (lane >> 4) * 4;
    #pragma unroll
    for (int m = 0; m < 4; ++m) {
        #pragma unroll
        for (int r = 0; r < 4; ++r) {
            int row = bm + m * 16 + crow0 + r;
            if (row >= M) continue;
            float ds = 0.f, dd = 0.f;
            #pragma unroll
            for (int n = 0; n < 4; ++n) {
                int col = bn + n * 16 + lrow;
                size_t idx = (size_t)row * DH + col;
                float v = acc[m][n][r];
                if (EPI) {
                    v += bias[col];
                    v = fmaxf(v, 0.f);
                    v += bf2f(resid[idx]);
                }
                Cb[idx] = f2bf(v);
                if (DOTS) { ds += v * wa[n]; dd += v * wb[n]; }
            }
            if (DOTS) {
                // reduce across the 16-lane group (all lanes share `row`)
                #pragma unroll
                for (int d = 1; d < 16; d <<= 1) {
                    ds += __shfl_xor(ds, d);
                    dd += __shfl_xor(dd, d);
                }
                if (lrow == 0) {
                    atomicAdd(&ssrc[row], ds);
                    atomicAdd(&sdst[row], dd);
                }
            }
        }
    }
}

// ------------------------------------------------------------------ launch
extern "C" void kernel_launch(void* const* d_in, const int* in_sizes, int n_in,
                              void* d_out, int out_size, void* d_ws, size_t ws_size,
                              hipStream_t stream) {
    const float* x    = (const float*)d_in[0];
    const int*   ei   = (const int*)d_in[1];
    const float* ea   = (const float*)d_in[2];
    const float* W0   = (const float*)d_in[3];
    const float* b0   = (const float*)d_in[4];
    const float* W1   = (const float*)d_in[5];
    const float* b1   = (const float*)d_in[6];
    const float* Wg   = (const float*)d_in[7];
    const float* bg   = (const float*)d_in[8];
    const float* a_src= (const float*)d_in[9];
    const float* a_dst= (const float*)d_in[10];
    const float* We   = (const float*)d_in[11];
    const float* a_e  = (const float*)d_in[12];
    const float* Ws   = (const float*)d_in[13];
    const float* Wn   = (const float*)d_in[14];
    const float* bm   = (const float*)d_in[15];
    float* out = (float*)d_out;

    const int N = in_sizes[0] / 3;
    const int E = in_sizes[1] / 2;
    const int Mpad = (N + 127) & ~127;
    const int* srcI = ei;
    const int* dstI = ei + E;

    char* p = (char*)d_ws;
    auto alloc = [&](size_t bytes) {
        void* r = (void*)p;
        p += (bytes + 255) & ~(size_t)255;
        return r;
    };
    size_t NBh = (size_t)Mpad * DH * sizeof(unsigned short);
    unsigned short* Hb0  = (unsigned short*)alloc(NBh);
    unsigned short* Hb1  = (unsigned short*)alloc(NBh);
    unsigned short* hgbf = (unsigned short*)alloc(NBh);   // reused as mean
    unsigned short* h1bf = (unsigned short*)alloc(NBh);
    unsigned short* Wt   = (unsigned short*)alloc((size_t)15 * DH * DH * sizeof(unsigned short));
    float* elogp = (float*)alloc((size_t)NLAYERS * E * sizeof(float));
    int*   csrc  = (int*)alloc((size_t)E * sizeof(int));
    int*   ceid  = (int*)alloc((size_t)E * sizeof(int));
    int*   off   = (int*)alloc((size_t)(N + 1) * sizeof(int));
    int*   cnt   = (int*)alloc((size_t)N * sizeof(int));
    int*   cur   = (int*)alloc((size_t)N * sizeof(int));
    float* invd  = (float*)alloc((size_t)N * sizeof(float));
    float* sdots = (float*)alloc((size_t)2 * N * sizeof(float));
    float* ssrc  = sdots;
    float* sdst  = sdots + N;
    float* weae  = (float*)alloc((size_t)NLAYERS * DE * sizeof(float));
    const int NBLK = (N + SEG - 1) / SEG;  // 98 for N=50000 (<=128)
    int* part = (int*)alloc((size_t)NBLK * sizeof(int));
    int* base = (int*)alloc((size_t)NBLK * sizeof(int));

    const int EB = (E + 255) / 256;
    const int NB4 = (N + 3) / 4;
    const int MB = Mpad / 128;

    // ---- CSR build
    hipMemsetAsync(cnt, 0, (size_t)N * sizeof(int), stream);
    hipMemsetAsync(cur, 0, (size_t)N * sizeof(int), stream);
    k_count<<<EB, 256, 0, stream>>>(dstI, cnt, E);
    k_part<<<NBLK, SEG, 0, stream>>>(cnt, part, N);
    k_scanp<<<1, 128, 0, stream>>>(part, base, off, NBLK, N, E);
    k_emit<<<NBLK, SEG, 0, stream>>>(cnt, base, off, invd, N);
    k_fill<<<EB, 256, 0, stream>>>(srcI, dstI, off, cur, csrc, ceid, E);

    // ---- h-independent edge terms (CSR-ordered, gather direction), weights
    k_we_ae<<<1, 256, 0, stream>>>(We, a_e, weae);
    k_elogit<<<EB, 256, 0, stream>>>(ea, weae, ceid, elogp, E);
    k_wt<<<dim3(8, 8, 15), dim3(32, 8), 0, stream>>>(Wg, Ws, Wn, Wt);

    // ---- input projection
    k_lin0<<<N, DH, 0, stream>>>(x, W0, b0, Hb0, N);

    // ---- residual blocks
    unsigned short* Hcur = Hb0;
    unsigned short* Hnxt = Hb1;
    for (int l = 0; l < NLAYERS; ++l) {
        const unsigned short* Wgt = Wt + (size_t)l * DH * DH;
        const unsigned short* Wst = Wt + (size_t)(5 + l) * DH * DH;
        const unsigned short* Wnt = Wt + (size_t)(10 + l) * DH * DH;
        unsigned short* meanbf = hgbf;  // hg dead after k_attn

        hipMemsetAsync(sdots, 0, (size_t)2 * N * sizeof(float), stream);
        k_gemm_mfma<0, 0, 1><<<dim3(MB, 2), 256, 0, stream>>>(
            Hcur, Wgt, nullptr, nullptr, nullptr, nullptr, hgbf, N,
            a_src + (size_t)l * DH, a_dst + (size_t)l * DH, ssrc, sdst);
        k_attn<<<NB4, 256, 0, stream>>>(off, csrc, ssrc, sdst, elogp + (size_t)l * E,
                                        hgbf, bg + (size_t)l * DH, h1bf, N);
        k_mean<<<NB4, 256, 0, stream>>>(off, csrc, h1bf, invd, meanbf, N);
        k_gemm_mfma<1, 1, 0><<<dim3(MB, 2), 256, 0, stream>>>(
            h1bf, Wst, meanbf, Wnt, bm + (size_t)l * DH, Hcur, Hnxt, N,
            nullptr, nullptr, nullptr, nullptr);

        unsigned short* tmp = Hcur; Hcur = Hnxt; Hnxt = tmp;
    }

    // ---- output projection
    k_out<<<NB4, 256, 0, stream>>>(Hcur, W1, b1, out, N);
}